// Round 9
// baseline (160.051 us; speedup 1.0000x reference)
//
#include <hip/hip_runtime.h>
#include <hip/hip_bf16.h>
#include <stdint.h>

// ---------------------------------------------------------------------------
// pcnn round 19: R18 base + packed-f32 (VOP3P) merge/relu — code-size probe.
//  - R18: setprio deletion = clean null -> scheduling family fully falsified.
//    Remaining theory: I-fetch (33KB unrolled body > 32KB L1I, 8 desynced
//    waves/CU). Full unroll is mandatory (reg arrays can't be runtime-
//    indexed); all liveness-touching restructures spill (R14-R17).
//  - This round: merge+relu pack written as f32x4 vector ops -> LLVM emits
//    v_pk_add_f32 / v_pk_max_f32 (2 f32/instr): pack ~24 -> ~12 instrs/px,
//    ~-19KB code, -1.6k VALU cyc/wave. Same values, same sum order ->
//    absmax bit-identical. Zero liveness delta.
//  - Logits merge vectorized the same way.
//  - Tripwires: VGPR 128, WRITE ~16.3MB, FETCH ~17.1MB, conflicts ~997k.
// ---------------------------------------------------------------------------

typedef short bf16x8 __attribute__((ext_vector_type(8)));
typedef float f32x4  __attribute__((ext_vector_type(4)));

// d_ws: WALL bf16 [8 layers][9 taps][32 o(permuted rows)][32 c] @0 (73728 u16)
//   l=0: conv0 (c<8), l=1..6: mid, l=7 rows<6: logits; l=7 rows>=6: wpost frags
// f32 @ byte 147456: BALL[8][32](permuted) @0, BP32[32] @256 (zero-padded bpost)
#define WSB_N     73728
#define WSB_EMB   6144
#define WSF_BYTE  147456
#define WSF_BALL  0
#define WSF_BP32  256

// LDS layout (bytes):
//   phase1: stage @0 (25*136*2=6800), inpk @6800 (6144), colb @12944 (1152)
//   phase2: smb @0 (25*98*4=9800; stage+inpk dead), colb persists
#define L_STAGE_STRIDE 136
#define L_INPK   6800
#define L_COLB   12944
#define L_POOL   14096
#define SMB_STRIDE 98

__device__ __forceinline__ float b2f(unsigned short u) {
  union { unsigned int u; float f; } v; v.u = ((unsigned int)u) << 16; return v.f;
}
__device__ __forceinline__ unsigned short f2b(float f) {
  union { float f; unsigned int u; } v; v.f = f;
  unsigned int r = v.u + 0x7fffu + ((v.u >> 16) & 1u);  // RNE
  return (unsigned short)(r >> 16);
}
__device__ __forceinline__ unsigned int pk2(float lo, float hi) {
  __hip_bfloat162 h = __float22bfloat162_rn(make_float2(lo, hi));
  union { __hip_bfloat162 h; unsigned int u; } v; v.h = h; return v.u;
}
__device__ __forceinline__ bool sniff_is_f32(const void* w0raw) {
  const unsigned short* q = (const unsigned short*)w0raw;
  int hits = 0;
  #pragma unroll
  for (int i = 0; i < 64; ++i) {
    unsigned int e = (q[i] >> 7) & 0xFFu;
    if (e >= 130u) ++hits;
  }
  return hits > 0;
}
__device__ __forceinline__ float ldw(const void* p, long idx, bool f32) {
  return f32 ? ((const float*)p)[idx] : b2f(((const unsigned short*)p)[idx]);
}
// C-row m -> B-k-slot permutation
__device__ __forceinline__ int kperm(int m) {
  return (m < 16) ? ((m >> 2) * 8 + (m & 3))
                  : (((m - 16) >> 2) * 8 + 4 + (m & 3));
}

// ---------------- weight pre-pack (identical to R12/R13, verified) ---------
__global__ void prep_weights(const void* __restrict__ w0,
                             const void* __restrict__ b0,
                             const void* __restrict__ wm,
                             const void* __restrict__ bm,
                             const void* __restrict__ wl,
                             const void* __restrict__ bl,
                             const void* __restrict__ wp,
                             const void* __restrict__ bp,
                             unsigned short* __restrict__ wsb,
                             float* __restrict__ wsf) {
  const bool f32 = sniff_is_f32(w0);
  int e = blockIdx.x * blockDim.x + threadIdx.x;
  if (e < WSB_N) {                        // WALL[l][t][o32][c32]
    int l = e / 9216, r = e % 9216, t = r / 1024, r2 = r % 1024;
    int o = r2 >> 5, c = r2 & 31;
    if (l == 7 && o >= 6) return;         // reserved for wpost frags
    float v = 0.f;
    if (l < 7) {
      int co = kperm(o);                  // original out-channel at row o
      if (co < 25) {
        if (l == 0) { if (c < 8)  v = ldw(w0, (co * 8 + c) * 9 + t, f32); }
        else        { if (c < 25) v = ldw(wm, (((l - 1) * 25 + co) * 25 + c) * 9 + t, f32); }
      }
    } else {
      if (c < 25) v = ldw(wl, (o * 25 + c) * 9 + t, f32);
    }
    wsb[e] = f2b(v);
  } else if (e < WSB_N + WSB_EMB) {
    // wpost frag pack: conceptual [hl2][chunk3][o32][k32], physical at
    // layer-7 rows >= 6: rowidx = hl*96+chunk*32+o -> (tap, row 6+rowidx%26)
    int idx = e - WSB_N;
    int hl = idx / 3072, rem = idx % 3072;
    int chunk = rem / 1024, r2 = rem % 1024;
    int o = r2 >> 5, k = r2 & 31;
    float w = (o < 18 && k < 25) ? ldw(wp, (o * 3 + chunk) * 25 + k, f32) : 0.f;
    unsigned short hi = f2b(w);
    unsigned short val = hl ? f2b(w - b2f(hi)) : hi;
    int rowidx = hl * 96 + chunk * 32 + o;
    int t = rowidx / 26, rr = 6 + rowidx % 26;
    wsb[7 * 9216 + t * 1024 + rr * 32 + k] = val;
  } else {
    int q = e - WSB_N - WSB_EMB;
    if (q < 256) {                        // BALL[l][32] (rows permuted, l<7)
      int l = q >> 5, m = q & 31;
      float v = 0.f;
      if (l < 7) {
        int co = kperm(m);
        if (co < 25) v = (l == 0) ? ldw(b0, co, f32) : ldw(bm, (l - 1) * 25 + co, f32);
      } else {
        if (m < 6) v = ldw(bl, m, f32);
      }
      wsf[WSF_BALL + q] = v;
    } else if (q < 288) {                 // BP32: zero-padded bpost
      int oc = q - 256;
      wsf[WSF_BP32 + oc] = (oc < 18) ? ldw(bp, oc, f32) : 0.f;
    }
  }
}

// ---------------- main kernel: one wave per 16 patches ---------------------
__global__ __launch_bounds__(64)
__attribute__((amdgpu_waves_per_eu(2, 2)))
void pcnn_mfma(
    const void* __restrict__ inp,
    const void* __restrict__ w0raw,
    const unsigned short* __restrict__ wsb,
    const float* __restrict__ wsf,
    void* __restrict__ out) {
  __shared__ __align__(16) unsigned char pool[L_POOL];
  short* stage = (short*)pool;              // [25px][136] phase 1
  short* inpk  = (short*)(pool + L_INPK);   // [hl2][ic3][b16][k32] phase 1
  float* colb  = (float*)(pool + L_COLB);   // [b16][18oc] both phases
  float* smb   = (float*)pool;              // [25px][98] phase 2

  const bool f32m = sniff_is_f32(w0raw);
  const int lane = threadIdx.x;         // 0..63
  const int col  = lane & 15;           // MFMA n (patch) / m-row group
  const int quad = lane >> 4;
  const long g   = blockIdx.x;          // group of 16 patches

  // ---- colors A-frags + bias: issue now, consumed after staging ----
  bf16x8 WC[2][3][2];
  #pragma unroll
  for (int hl = 0; hl < 2; ++hl)
    #pragma unroll
    for (int ch = 0; ch < 3; ++ch)
      #pragma unroll
      for (int hf = 0; hf < 2; ++hf) {
        const int rowidx = hl * 96 + ch * 32 + hf * 16 + col;
        const int t = rowidx / 26, rr = 6 + rowidx % 26;
        WC[hl][ch][hf] = *(const bf16x8*)(wsb + 7 * 9216 + t * 1024 + rr * 32 + quad * 8);
      }
  f32x4 c0 = *(const f32x4*)(wsf + WSF_BP32 + quad * 4);
  f32x4 c1 = *(const f32x4*)(wsf + WSF_BP32 + 16 + quad * 4);

  // ---- zero inpk pad slots k=25..31 (garbage NaN x 0-weight = NaN!) ----
  for (int i = lane; i < 672; i += 64) {
    int s = 25 + i % 7, rest = i / 7;     // rest = (hl*3+ic)*16+b
    inpk[rest * 32 + s] = 0;
  }

  // ---- stage input [b][8c][25px] -> stage[px][b*8+c] + inpk hi/lo ----
  #pragma unroll 1
  for (int c0i = 0; c0i < 3200; c0i += 1600) {
    float v[25];
    #pragma unroll
    for (int j = 0; j < 25; ++j)
      v[j] = ldw(inp, g * 3200 + c0i + j * 64 + lane, f32m);
    #pragma unroll
    for (int j = 0; j < 25; ++j) {
      const int e = c0i + j * 64 + lane;
      int b = e / 200, r = e % 200, c = r / 25, px = r % 25;
      unsigned short hi = f2b(v[j]);
      stage[px * L_STAGE_STRIDE + b * 8 + c] = hi;
      if (c < 3) {
        inpk[((0 * 3 + c) * 16 + b) * 32 + px] = hi;
        inpk[((1 * 3 + c) * 16 + b) * 32 + px] = f2b(v[j] - b2f(hi));
      }
    }
  }
  __asm__ volatile("s_waitcnt lgkmcnt(0)" ::: "memory");

  // ---- colors GEMM: 18 MFMAs, double-bf16 ----
  #pragma unroll
  for (int ch = 0; ch < 3; ++ch) {
    bf16x8 Bhi = *(const bf16x8*)(inpk + ((0 * 3 + ch) * 16 + col) * 32 + quad * 8);
    bf16x8 Blo = *(const bf16x8*)(inpk + ((1 * 3 + ch) * 16 + col) * 32 + quad * 8);
    c0 = __builtin_amdgcn_mfma_f32_16x16x32_bf16(WC[0][ch][0], Bhi, c0, 0, 0, 0);
    c0 = __builtin_amdgcn_mfma_f32_16x16x32_bf16(WC[0][ch][0], Blo, c0, 0, 0, 0);
    c0 = __builtin_amdgcn_mfma_f32_16x16x32_bf16(WC[1][ch][0], Bhi, c0, 0, 0, 0);
    c1 = __builtin_amdgcn_mfma_f32_16x16x32_bf16(WC[0][ch][1], Bhi, c1, 0, 0, 0);
    c1 = __builtin_amdgcn_mfma_f32_16x16x32_bf16(WC[0][ch][1], Blo, c1, 0, 0, 0);
    c1 = __builtin_amdgcn_mfma_f32_16x16x32_bf16(WC[1][ch][1], Bhi, c1, 0, 0, 0);
  }
  // lane (patch=col): c0 regs r -> oc quad*4+r; c1 regs -> oc 16+quad*4+r
  #pragma unroll
  for (int r = 0; r < 4; ++r) colb[col * 18 + quad * 4 + r] = c0[r];
  if (quad == 0) { colb[col * 18 + 16] = c1[0]; colb[col * 18 + 17] = c1[1]; }

  // ---- layer-0 B-frags: quad0 holds ch0..7, other quads zero ----
  bf16x8 X[25], Y[25];
  #pragma unroll
  for (int p = 0; p < 25; ++p) {
    union { bf16x8 v; uint4 q4; } t;
    t.q4 = make_uint4(0u, 0u, 0u, 0u);
    if (quad == 0) t.q4 = *(const uint4*)(stage + p * L_STAGE_STRIDE + col * 8);
    X[p] = t.v;
  }

  // ---- packed-f32 merge + relu + bf16 pack (VOP3P: pk_add/pk_max) ----
  const f32x4 ZV = {0.f, 0.f, 0.f, 0.f};
  auto packout = [&](const f32x4& e0, const f32x4& o0,
                     const f32x4& e1, const f32x4& o1, bf16x8& dst) {
    f32x4 s0 = __builtin_elementwise_max(e0 + o0, ZV);  // 2 pk_add + 2 pk_max
    f32x4 s1 = __builtin_elementwise_max(e1 + o1, ZV);
    union { bf16x8 v; unsigned int uu[4]; } nb;
    nb.uu[0] = pk2(s0[0], s0[1]);
    nb.uu[1] = pk2(s0[2], s0[3]);
    nb.uu[2] = pk2(s1[0], s1[1]);
    nb.uu[3] = pk2(s1[2], s1[3]);
    dst = nb.v;
  };

  // ---- conv layer: deferred pack, packed-f32 epilogue ----
  auto conv = [&](const bf16x8 (&in)[25], bf16x8 (&outp)[25], int l) {
    const unsigned short* WA = wsb + l * 9216;
    bf16x8 A0[9], A1[9];
    #pragma unroll
    for (int t = 0; t < 9; ++t) {
      A0[t] = *(const bf16x8*)(WA + t * 1024 + col * 32 + quad * 8);
      A1[t] = *(const bf16x8*)(WA + t * 1024 + (16 + col) * 32 + quad * 8);
    }
    const f32x4 bias0 = *(const f32x4*)(wsf + WSF_BALL + l * 32 + quad * 4);
    const f32x4 bias1 = *(const f32x4*)(wsf + WSF_BALL + l * 32 + 16 + quad * 4);
    f32x4 p0e, p0o, p1e, p1o;             // previous pixel's accumulators
    #pragma unroll
    for (int p = 0; p < 25; ++p) {
      const int py = p / 5, pxx = p % 5;
      f32x4 a0e = bias0, a1e = bias1;
      f32x4 a0o = ZV, a1o = ZV;
      #pragma unroll
      for (int dy = -1; dy <= 1; ++dy)
        #pragma unroll
        for (int dx = -1; dx <= 1; ++dx)
          if ((unsigned)(py + dy) < 5u && (unsigned)(pxx + dx) < 5u) {
            const int t = (dy + 1) * 3 + (dx + 1);
            const int q = p + dy * 5 + dx;
            if (t & 1) {
              a0o = __builtin_amdgcn_mfma_f32_16x16x32_bf16(A0[t], in[q], a0o, 0, 0, 0);
              a1o = __builtin_amdgcn_mfma_f32_16x16x32_bf16(A1[t], in[q], a1o, 0, 0, 0);
            } else {
              a0e = __builtin_amdgcn_mfma_f32_16x16x32_bf16(A0[t], in[q], a0e, 0, 0, 0);
              a1e = __builtin_amdgcn_mfma_f32_16x16x32_bf16(A1[t], in[q], a1e, 0, 0, 0);
            }
          }
      if (p > 0)                          // pack PREVIOUS pixel (no stall)
        packout(p0e, p0o, p1e, p1o, outp[p - 1]);
      p0e = a0e; p0o = a0o; p1e = a1e; p1o = a1o;   // SSA-renamed, no movs
    }
    packout(p0e, p0o, p1e, p1o, outp[24]);
  };

  conv(X, Y, 0);
  #pragma unroll 1
  for (int i = 0; i < 3; ++i) {
    conv(Y, X, 2 * i + 1);
    conv(X, Y, 2 * i + 2);
  }
  // final hidden in Y

  // ---- logits + deferred softmax tail -> smb ----
  {
    const unsigned short* WA = wsb + 7 * 9216;
    bf16x8 A[9];
    #pragma unroll
    for (int t = 0; t < 9; ++t)
      A[t] = *(const bf16x8*)(WA + t * 1024 + col * 32 + quad * 8);
    const f32x4 biasl = *(const f32x4*)(wsf + WSF_BALL + 7 * 32 + quad * 4);
    f32x4 pa;                              // previous pixel's merged logits
    auto tail = [&](const f32x4& a, int p) {
      float l4 = __shfl_xor(a[0], 16);
      float l5 = __shfl_xor(a[1], 16);
      if (quad == 0) {
        float m = fmaxf(fmaxf(fmaxf(a[0], a[1]), fmaxf(a[2], a[3])), fmaxf(l4, l5));
        float e0 = __expf(a[0] - m), e1 = __expf(a[1] - m), e2 = __expf(a[2] - m);
        float e3 = __expf(a[3] - m), e4 = __expf(l4 - m), e5 = __expf(l5 - m);
        float inv = 1.f / (e0 + e1 + e2 + e3 + e4 + e5);
        float* sp = smb + p * SMB_STRIDE + col * 6;
        sp[0] = e0 * inv; sp[1] = e1 * inv; sp[2] = e2 * inv;
        sp[3] = e3 * inv; sp[4] = e4 * inv; sp[5] = e5 * inv;
      }
    };
    #pragma unroll
    for (int p = 0; p < 25; ++p) {
      const int py = p / 5, pxx = p % 5;
      f32x4 ae = biasl, ao = {0.f, 0.f, 0.f, 0.f};
      #pragma unroll
      for (int dy = -1; dy <= 1; ++dy)
        #pragma unroll
        for (int dx = -1; dx <= 1; ++dx)
          if ((unsigned)(py + dy) < 5u && (unsigned)(pxx + dx) < 5u) {
            const int t = (dy + 1) * 3 + (dx + 1);
            const int q = p + dy * 5 + dx;
            if (t & 1)
              ao = __builtin_amdgcn_mfma_f32_16x16x32_bf16(A[t], Y[q], ao, 0, 0, 0);
            else
              ae = __builtin_amdgcn_mfma_f32_16x16x32_bf16(A[t], Y[q], ae, 0, 0, 0);
          }
      if (p > 0) tail(pa, p - 1);          // softmax for PREVIOUS pixel
      pa = ae + ao;                        // 2x v_pk_add_f32
    }
    tail(pa, 24);
  }
  __asm__ volatile("s_waitcnt lgkmcnt(0)" ::: "memory");

  // ---- mix + store: out[b][c][p] = sum_w colors[b][c*6+w] * sm[p][b][w] ----
  for (int e = lane; e < 1200; e += 64) {
    int b = e / 75, r = e % 75, c = r / 25, p = r % 25;
    float v = 0.f;
    #pragma unroll
    for (int w = 0; w < 6; ++w)
      v = fmaf(colb[b * 18 + c * 6 + w], smb[p * SMB_STRIDE + b * 6 + w], v);
    const long oidx = g * 1200 + e;
    if (f32m) ((float*)out)[oidx] = v;
    else      ((unsigned short*)out)[oidx] = f2b(v);
  }
}

extern "C" void kernel_launch(void* const* d_in, const int* in_sizes, int n_in,
                              void* d_out, int out_size, void* d_ws, size_t ws_size,
                              hipStream_t stream) {
  unsigned short* wsb = (unsigned short*)d_ws;
  float* wsf = (float*)((char*)d_ws + WSF_BYTE);
  const int B = in_sizes[0] / 200;  // 32768

  const int prep_n = WSB_N + WSB_EMB + 288;  // 80160
  prep_weights<<<(prep_n + 255) / 256, 256, 0, stream>>>(
      d_in[1], d_in[2], d_in[3], d_in[4], d_in[5], d_in[6], d_in[7], d_in[8],
      wsb, wsf);
  pcnn_mfma<<<B / 16, 64, 0, stream>>>(d_in[0], d_in[1], wsb, wsf, d_out);
}

// Round 11
// 158.466 us; speedup vs baseline: 1.0100x; 1.0100x over previous
//
#include <hip/hip_runtime.h>
#include <hip/hip_bf16.h>
#include <stdint.h>

// ---------------------------------------------------------------------------
// pcnn round 21 (= R20 resubmit; container failed, no data).
// Pixel-PAIR interleave with IMMEDIATE pair-end pack.
//  - Theory (fits all 9 data rounds): MFMA acc-chain latency L~200cy;
//    cluster = 4 chains x depth 5 -> 5L ~ 1000cy ~ measured 1030cy/cluster.
//    Pairing puts same-chain MFMAs ~8 issues apart (halves exposed latency).
//  - R14 failed ONLY on registers: deferred-PAIR pack carried 64 acc regs.
//    This variant packs at pair end (carried = 0): acc liveness = 32 regs
//    current pair = EQUAL to R13 (16 current + 16 prev deferred).
//  - pA's pack is covered by pB's issue stream; pB's pack eats ~150cy/pair
//    (13 pairs/layer) -- small vs saved 5L/pair.
//  - Base = R18 (no setprio, scalar pack, strides 136/98, colors GEMM).
//  - Tripwires: VGPR 128, WRITE ~16.3MB, FETCH ~17.1MB, conflicts ~997k.
// ---------------------------------------------------------------------------

typedef short bf16x8 __attribute__((ext_vector_type(8)));
typedef float f32x4  __attribute__((ext_vector_type(4)));

// d_ws: WALL bf16 [8 layers][9 taps][32 o(permuted rows)][32 c] @0 (73728 u16)
//   l=0: conv0 (c<8), l=1..6: mid, l=7 rows<6: logits; l=7 rows>=6: wpost frags
// f32 @ byte 147456: BALL[8][32](permuted) @0, BP32[32] @256 (zero-padded bpost)
#define WSB_N     73728
#define WSB_EMB   6144
#define WSF_BYTE  147456
#define WSF_BALL  0
#define WSF_BP32  256

// LDS layout (bytes):
//   phase1: stage @0 (25*136*2=6800), inpk @6800 (6144), colb @12944 (1152)
//   phase2: smb @0 (25*98*4=9800; stage+inpk dead), colb persists
#define L_STAGE_STRIDE 136
#define L_INPK   6800
#define L_COLB   12944
#define L_POOL   14096
#define SMB_STRIDE 98

__device__ __forceinline__ float b2f(unsigned short u) {
  union { unsigned int u; float f; } v; v.u = ((unsigned int)u) << 16; return v.f;
}
__device__ __forceinline__ unsigned short f2b(float f) {
  union { float f; unsigned int u; } v; v.f = f;
  unsigned int r = v.u + 0x7fffu + ((v.u >> 16) & 1u);  // RNE
  return (unsigned short)(r >> 16);
}
__device__ __forceinline__ unsigned int pk2(float lo, float hi) {
  __hip_bfloat162 h = __float22bfloat162_rn(make_float2(lo, hi));
  union { __hip_bfloat162 h; unsigned int u; } v; v.h = h; return v.u;
}
__device__ __forceinline__ bool sniff_is_f32(const void* w0raw) {
  const unsigned short* q = (const unsigned short*)w0raw;
  int hits = 0;
  #pragma unroll
  for (int i = 0; i < 64; ++i) {
    unsigned int e = (q[i] >> 7) & 0xFFu;
    if (e >= 130u) ++hits;
  }
  return hits > 0;
}
__device__ __forceinline__ float ldw(const void* p, long idx, bool f32) {
  return f32 ? ((const float*)p)[idx] : b2f(((const unsigned short*)p)[idx]);
}
// C-row m -> B-k-slot permutation
__device__ __forceinline__ int kperm(int m) {
  return (m < 16) ? ((m >> 2) * 8 + (m & 3))
                  : (((m - 16) >> 2) * 8 + 4 + (m & 3));
}

// ---------------- weight pre-pack (identical to R12/R13, verified) ---------
__global__ void prep_weights(const void* __restrict__ w0,
                             const void* __restrict__ b0,
                             const void* __restrict__ wm,
                             const void* __restrict__ bm,
                             const void* __restrict__ wl,
                             const void* __restrict__ bl,
                             const void* __restrict__ wp,
                             const void* __restrict__ bp,
                             unsigned short* __restrict__ wsb,
                             float* __restrict__ wsf) {
  const bool f32 = sniff_is_f32(w0);
  int e = blockIdx.x * blockDim.x + threadIdx.x;
  if (e < WSB_N) {                        // WALL[l][t][o32][c32]
    int l = e / 9216, r = e % 9216, t = r / 1024, r2 = r % 1024;
    int o = r2 >> 5, c = r2 & 31;
    if (l == 7 && o >= 6) return;         // reserved for wpost frags
    float v = 0.f;
    if (l < 7) {
      int co = kperm(o);                  // original out-channel at row o
      if (co < 25) {
        if (l == 0) { if (c < 8)  v = ldw(w0, (co * 8 + c) * 9 + t, f32); }
        else        { if (c < 25) v = ldw(wm, (((l - 1) * 25 + co) * 25 + c) * 9 + t, f32); }
      }
    } else {
      if (c < 25) v = ldw(wl, (o * 25 + c) * 9 + t, f32);
    }
    wsb[e] = f2b(v);
  } else if (e < WSB_N + WSB_EMB) {
    // wpost frag pack: conceptual [hl2][chunk3][o32][k32], physical at
    // layer-7 rows >= 6: rowidx = hl*96+chunk*32+o -> (tap, row 6+rowidx%26)
    int idx = e - WSB_N;
    int hl = idx / 3072, rem = idx % 3072;
    int chunk = rem / 1024, r2 = rem % 1024;
    int o = r2 >> 5, k = r2 & 31;
    float w = (o < 18 && k < 25) ? ldw(wp, (o * 3 + chunk) * 25 + k, f32) : 0.f;
    unsigned short hi = f2b(w);
    unsigned short val = hl ? f2b(w - b2f(hi)) : hi;
    int rowidx = hl * 96 + chunk * 32 + o;
    int t = rowidx / 26, rr = 6 + rowidx % 26;
    wsb[7 * 9216 + t * 1024 + rr * 32 + k] = val;
  } else {
    int q = e - WSB_N - WSB_EMB;
    if (q < 256) {                        // BALL[l][32] (rows permuted, l<7)
      int l = q >> 5, m = q & 31;
      float v = 0.f;
      if (l < 7) {
        int co = kperm(m);
        if (co < 25) v = (l == 0) ? ldw(b0, co, f32) : ldw(bm, (l - 1) * 25 + co, f32);
      } else {
        if (m < 6) v = ldw(bl, m, f32);
      }
      wsf[WSF_BALL + q] = v;
    } else if (q < 288) {                 // BP32: zero-padded bpost
      int oc = q - 256;
      wsf[WSF_BP32 + oc] = (oc < 18) ? ldw(bp, oc, f32) : 0.f;
    }
  }
}

// ---------------- main kernel: one wave per 16 patches ---------------------
__global__ __launch_bounds__(64)
__attribute__((amdgpu_waves_per_eu(2, 2)))
void pcnn_mfma(
    const void* __restrict__ inp,
    const void* __restrict__ w0raw,
    const unsigned short* __restrict__ wsb,
    const float* __restrict__ wsf,
    void* __restrict__ out) {
  __shared__ __align__(16) unsigned char pool[L_POOL];
  short* stage = (short*)pool;              // [25px][136] phase 1
  short* inpk  = (short*)(pool + L_INPK);   // [hl2][ic3][b16][k32] phase 1
  float* colb  = (float*)(pool + L_COLB);   // [b16][18oc] both phases
  float* smb   = (float*)pool;              // [25px][98] phase 2

  const bool f32m = sniff_is_f32(w0raw);
  const int lane = threadIdx.x;         // 0..63
  const int col  = lane & 15;           // MFMA n (patch) / m-row group
  const int quad = lane >> 4;
  const long g   = blockIdx.x;          // group of 16 patches

  // ---- colors A-frags + bias: issue now, consumed after staging ----
  bf16x8 WC[2][3][2];
  #pragma unroll
  for (int hl = 0; hl < 2; ++hl)
    #pragma unroll
    for (int ch = 0; ch < 3; ++ch)
      #pragma unroll
      for (int hf = 0; hf < 2; ++hf) {
        const int rowidx = hl * 96 + ch * 32 + hf * 16 + col;
        const int t = rowidx / 26, rr = 6 + rowidx % 26;
        WC[hl][ch][hf] = *(const bf16x8*)(wsb + 7 * 9216 + t * 1024 + rr * 32 + quad * 8);
      }
  f32x4 c0 = *(const f32x4*)(wsf + WSF_BP32 + quad * 4);
  f32x4 c1 = *(const f32x4*)(wsf + WSF_BP32 + 16 + quad * 4);

  // ---- zero inpk pad slots k=25..31 (garbage NaN x 0-weight = NaN!) ----
  for (int i = lane; i < 672; i += 64) {
    int s = 25 + i % 7, rest = i / 7;     // rest = (hl*3+ic)*16+b
    inpk[rest * 32 + s] = 0;
  }

  // ---- stage input [b][8c][25px] -> stage[px][b*8+c] + inpk hi/lo ----
  #pragma unroll 1
  for (int c0i = 0; c0i < 3200; c0i += 1600) {
    float v[25];
    #pragma unroll
    for (int j = 0; j < 25; ++j)
      v[j] = ldw(inp, g * 3200 + c0i + j * 64 + lane, f32m);
    #pragma unroll
    for (int j = 0; j < 25; ++j) {
      const int e = c0i + j * 64 + lane;
      int b = e / 200, r = e % 200, c = r / 25, px = r % 25;
      unsigned short hi = f2b(v[j]);
      stage[px * L_STAGE_STRIDE + b * 8 + c] = hi;
      if (c < 3) {
        inpk[((0 * 3 + c) * 16 + b) * 32 + px] = hi;
        inpk[((1 * 3 + c) * 16 + b) * 32 + px] = f2b(v[j] - b2f(hi));
      }
    }
  }
  __asm__ volatile("s_waitcnt lgkmcnt(0)" ::: "memory");

  // ---- colors GEMM: 18 MFMAs, double-bf16 ----
  #pragma unroll
  for (int ch = 0; ch < 3; ++ch) {
    bf16x8 Bhi = *(const bf16x8*)(inpk + ((0 * 3 + ch) * 16 + col) * 32 + quad * 8);
    bf16x8 Blo = *(const bf16x8*)(inpk + ((1 * 3 + ch) * 16 + col) * 32 + quad * 8);
    c0 = __builtin_amdgcn_mfma_f32_16x16x32_bf16(WC[0][ch][0], Bhi, c0, 0, 0, 0);
    c0 = __builtin_amdgcn_mfma_f32_16x16x32_bf16(WC[0][ch][0], Blo, c0, 0, 0, 0);
    c0 = __builtin_amdgcn_mfma_f32_16x16x32_bf16(WC[1][ch][0], Bhi, c0, 0, 0, 0);
    c1 = __builtin_amdgcn_mfma_f32_16x16x32_bf16(WC[0][ch][1], Bhi, c1, 0, 0, 0);
    c1 = __builtin_amdgcn_mfma_f32_16x16x32_bf16(WC[0][ch][1], Blo, c1, 0, 0, 0);
    c1 = __builtin_amdgcn_mfma_f32_16x16x32_bf16(WC[1][ch][1], Bhi, c1, 0, 0, 0);
  }
  // lane (patch=col): c0 regs r -> oc quad*4+r; c1 regs -> oc 16+quad*4+r
  #pragma unroll
  for (int r = 0; r < 4; ++r) colb[col * 18 + quad * 4 + r] = c0[r];
  if (quad == 0) { colb[col * 18 + 16] = c1[0]; colb[col * 18 + 17] = c1[1]; }

  // ---- layer-0 B-frags: quad0 holds ch0..7, other quads zero ----
  bf16x8 X[25], Y[25];
  #pragma unroll
  for (int p = 0; p < 25; ++p) {
    union { bf16x8 v; uint4 q4; } t;
    t.q4 = make_uint4(0u, 0u, 0u, 0u);
    if (quad == 0) t.q4 = *(const uint4*)(stage + p * L_STAGE_STRIDE + col * 8);
    X[p] = t.v;
  }

  // scalar merge+relu+pack (R18-verified epilogue)
  auto packout = [&](const f32x4& e0, const f32x4& o0,
                     const f32x4& e1, const f32x4& o1, bf16x8& dst) {
    union { bf16x8 v; unsigned int uu[4]; } nb;
    nb.uu[0] = pk2(fmaxf(e0[0] + o0[0], 0.f), fmaxf(e0[1] + o0[1], 0.f));
    nb.uu[1] = pk2(fmaxf(e0[2] + o0[2], 0.f), fmaxf(e0[3] + o0[3], 0.f));
    nb.uu[2] = pk2(fmaxf(e1[0] + o1[0], 0.f), fmaxf(e1[1] + o1[1], 0.f));
    nb.uu[3] = pk2(fmaxf(e1[2] + o1[2], 0.f), fmaxf(e1[3] + o1[3], 0.f));
    dst = nb.v;
  };

  // ---- conv layer: pixel-PAIR interleaved chains, pack at pair end ----
  auto conv = [&](const bf16x8 (&in)[25], bf16x8 (&outp)[25], int l) {
    const unsigned short* WA = wsb + l * 9216;
    bf16x8 A0[9], A1[9];
    #pragma unroll
    for (int t = 0; t < 9; ++t) {
      A0[t] = *(const bf16x8*)(WA + t * 1024 + col * 32 + quad * 8);
      A1[t] = *(const bf16x8*)(WA + t * 1024 + (16 + col) * 32 + quad * 8);
    }
    const f32x4 bias0 = *(const f32x4*)(wsf + WSF_BALL + l * 32 + quad * 4);
    const f32x4 bias1 = *(const f32x4*)(wsf + WSF_BALL + l * 32 + 16 + quad * 4);
    #pragma unroll
    for (int pp = 0; pp < 13; ++pp) {
      const int pA = 2 * pp, pB = 2 * pp + 1;   // pB==25 invalid at pp==12
      f32x4 aA0e = bias0, aA1e = bias1;
      f32x4 aA0o = {0.f, 0.f, 0.f, 0.f}, aA1o = {0.f, 0.f, 0.f, 0.f};
      f32x4 aB0e = bias0, aB1e = bias1;
      f32x4 aB0o = {0.f, 0.f, 0.f, 0.f}, aB1o = {0.f, 0.f, 0.f, 0.f};
      #pragma unroll
      for (int t = 0; t < 9; ++t) {
        const int dy = t / 3 - 1, dx = t % 3 - 1;
        {
          const int py = pA / 5, pxx = pA % 5;
          if ((unsigned)(py + dy) < 5u && (unsigned)(pxx + dx) < 5u) {
            const int q = pA + dy * 5 + dx;
            if (t & 1) {
              aA0o = __builtin_amdgcn_mfma_f32_16x16x32_bf16(A0[t], in[q], aA0o, 0, 0, 0);
              aA1o = __builtin_amdgcn_mfma_f32_16x16x32_bf16(A1[t], in[q], aA1o, 0, 0, 0);
            } else {
              aA0e = __builtin_amdgcn_mfma_f32_16x16x32_bf16(A0[t], in[q], aA0e, 0, 0, 0);
              aA1e = __builtin_amdgcn_mfma_f32_16x16x32_bf16(A1[t], in[q], aA1e, 0, 0, 0);
            }
          }
        }
        if (pB < 25) {
          const int py = pB / 5, pxx = pB % 5;
          if ((unsigned)(py + dy) < 5u && (unsigned)(pxx + dx) < 5u) {
            const int q = pB + dy * 5 + dx;
            if (t & 1) {
              aB0o = __builtin_amdgcn_mfma_f32_16x16x32_bf16(A0[t], in[q], aB0o, 0, 0, 0);
              aB1o = __builtin_amdgcn_mfma_f32_16x16x32_bf16(A1[t], in[q], aB1o, 0, 0, 0);
            } else {
              aB0e = __builtin_amdgcn_mfma_f32_16x16x32_bf16(A0[t], in[q], aB0e, 0, 0, 0);
              aB1e = __builtin_amdgcn_mfma_f32_16x16x32_bf16(A1[t], in[q], aB1e, 0, 0, 0);
            }
          }
        }
      }
      // pack at PAIR end: pA covered by pB's issue stream; pB ~150cy stall.
      // Carried-over state: ZERO (acc liveness == R13's 32 regs).
      packout(aA0e, aA0o, aA1e, aA1o, outp[pA]);
      if (pB < 25) packout(aB0e, aB0o, aB1e, aB1o, outp[pB]);
    }
  };

  conv(X, Y, 0);
  #pragma unroll 1
  for (int i = 0; i < 3; ++i) {
    conv(Y, X, 2 * i + 1);
    conv(X, Y, 2 * i + 2);
  }
  // final hidden in Y

  // ---- logits: pixel-PAIR interleaved + immediate softmax tails -> smb ----
  {
    const unsigned short* WA = wsb + 7 * 9216;
    bf16x8 A[9];
    #pragma unroll
    for (int t = 0; t < 9; ++t)
      A[t] = *(const bf16x8*)(WA + t * 1024 + col * 32 + quad * 8);
    const f32x4 biasl = *(const f32x4*)(wsf + WSF_BALL + 7 * 32 + quad * 4);
    auto tail = [&](const f32x4& a, int p) {
      float l4 = __shfl_xor(a[0], 16);
      float l5 = __shfl_xor(a[1], 16);
      if (quad == 0) {
        float m = fmaxf(fmaxf(fmaxf(a[0], a[1]), fmaxf(a[2], a[3])), fmaxf(l4, l5));
        float e0 = __expf(a[0] - m), e1 = __expf(a[1] - m), e2 = __expf(a[2] - m);
        float e3 = __expf(a[3] - m), e4 = __expf(l4 - m), e5 = __expf(l5 - m);
        float inv = 1.f / (e0 + e1 + e2 + e3 + e4 + e5);
        float* sp = smb + p * SMB_STRIDE + col * 6;
        sp[0] = e0 * inv; sp[1] = e1 * inv; sp[2] = e2 * inv;
        sp[3] = e3 * inv; sp[4] = e4 * inv; sp[5] = e5 * inv;
      }
    };
    #pragma unroll
    for (int pp = 0; pp < 13; ++pp) {
      const int pA = 2 * pp, pB = 2 * pp + 1;
      f32x4 aeA = biasl, aoA = {0.f, 0.f, 0.f, 0.f};
      f32x4 aeB = biasl, aoB = {0.f, 0.f, 0.f, 0.f};
      #pragma unroll
      for (int t = 0; t < 9; ++t) {
        const int dy = t / 3 - 1, dx = t % 3 - 1;
        {
          const int py = pA / 5, pxx = pA % 5;
          if ((unsigned)(py + dy) < 5u && (unsigned)(pxx + dx) < 5u) {
            const int q = pA + dy * 5 + dx;
            if (t & 1) aoA = __builtin_amdgcn_mfma_f32_16x16x32_bf16(A[t], Y[q], aoA, 0, 0, 0);
            else       aeA = __builtin_amdgcn_mfma_f32_16x16x32_bf16(A[t], Y[q], aeA, 0, 0, 0);
          }
        }
        if (pB < 25) {
          const int py = pB / 5, pxx = pB % 5;
          if ((unsigned)(py + dy) < 5u && (unsigned)(pxx + dx) < 5u) {
            const int q = pB + dy * 5 + dx;
            if (t & 1) aoB = __builtin_amdgcn_mfma_f32_16x16x32_bf16(A[t], Y[q], aoB, 0, 0, 0);
            else       aeB = __builtin_amdgcn_mfma_f32_16x16x32_bf16(A[t], Y[q], aeB, 0, 0, 0);
          }
        }
      }
      f32x4 a;
      a[0] = aeA[0] + aoA[0]; a[1] = aeA[1] + aoA[1];
      a[2] = aeA[2] + aoA[2]; a[3] = aeA[3] + aoA[3];
      tail(a, pA);
      if (pB < 25) {
        f32x4 b;
        b[0] = aeB[0] + aoB[0]; b[1] = aeB[1] + aoB[1];
        b[2] = aeB[2] + aoB[2]; b[3] = aeB[3] + aoB[3];
        tail(b, pB);
      }
    }
  }
  __asm__ volatile("s_waitcnt lgkmcnt(0)" ::: "memory");

  // ---- mix + store: out[b][c][p] = sum_w colors[b][c*6+w] * sm[p][b][w] ----
  for (int e = lane; e < 1200; e += 64) {
    int b = e / 75, r = e % 75, c = r / 25, p = r % 25;
    float v = 0.f;
    #pragma unroll
    for (int w = 0; w < 6; ++w)
      v = fmaf(colb[b * 18 + c * 6 + w], smb[p * SMB_STRIDE + b * 6 + w], v);
    const long oidx = g * 1200 + e;
    if (f32m) ((float*)out)[oidx] = v;
    else      ((unsigned short*)out)[oidx] = f2b(v);
  }
}

extern "C" void kernel_launch(void* const* d_in, const int* in_sizes, int n_in,
                              void* d_out, int out_size, void* d_ws, size_t ws_size,
                              hipStream_t stream) {
  unsigned short* wsb = (unsigned short*)d_ws;
  float* wsf = (float*)((char*)d_ws + WSF_BYTE);
  const int B = in_sizes[0] / 200;  // 32768

  const int prep_n = WSB_N + WSB_EMB + 288;  // 80160
  prep_weights<<<(prep_n + 255) / 256, 256, 0, stream>>>(
      d_in[1], d_in[2], d_in[3], d_in[4], d_in[5], d_in[6], d_in[7], d_in[8],
      wsb, wsf);
  pcnn_mfma<<<B / 16, 64, 0, stream>>>(d_in[0], d_in[1], wsb, wsf, d_out);
}